// Round 4
// baseline (249.091 us; speedup 1.0000x reference)
//
#include <hip/hip_runtime.h>

typedef unsigned short u16;
typedef unsigned int   u32;
typedef __attribute__((ext_vector_type(8))) short bf16x8;
typedef __attribute__((ext_vector_type(4))) float f32x4;
typedef __attribute__((ext_vector_type(4))) unsigned short u16x4;

#define N_NODES 50000
#define N_EDGES 800000
#define D_IN    512
#define D_OUT   256
#define M_PAD   50048   // 391 * 128

__device__ __forceinline__ u16 f2bf(float f) {
  u32 u = __float_as_uint(f);
  return (u16)((u + 0x7FFFu + ((u >> 16) & 1u)) >> 16);  // RNE
}
__device__ __forceinline__ float bf2f(u16 h) {
  return __uint_as_float(((u32)h) << 16);
}

__device__ __forceinline__ void gload_lds16(const void* g, void* l) {
  __builtin_amdgcn_global_load_lds(
      (const __attribute__((address_space(1))) unsigned int*)g,
      (__attribute__((address_space(3))) unsigned int*)l, 16, 0, 0);
}

// ---- zero the counts array (replaces 60us rocclr fillBuffer) ----
__global__ void k_zero(int* __restrict__ c, int n) {
  int i = blockIdx.x * blockDim.x + threadIdx.x;
  if (i < n) c[i] = 0;
}

// ---- x (fp32) -> xb (bf16), zero-pad rows [N_NODES, M_PAD) ----
__global__ void k_convert_x(const float* __restrict__ x, u16* __restrict__ xb,
                            long n_valid, long n_total) {
  long i = ((long)blockIdx.x * blockDim.x + threadIdx.x) * 8;
  if (i >= n_total) return;
  uint4 o;
  if (i < n_valid) {
    float4 f0 = *(const float4*)(x + i);
    float4 f1 = *(const float4*)(x + i + 4);
    o.x = (u32)f2bf(f0.x) | ((u32)f2bf(f0.y) << 16);
    o.y = (u32)f2bf(f0.z) | ((u32)f2bf(f0.w) << 16);
    o.z = (u32)f2bf(f1.x) | ((u32)f2bf(f1.y) << 16);
    o.w = (u32)f2bf(f1.z) | ((u32)f2bf(f1.w) << 16);
  } else {
    o.x = o.y = o.z = o.w = 0u;
  }
  *(uint4*)(xb + i) = o;
}

// ---- W [K=512][N=256] fp32 -> Wt [N=256][K=512] bf16 ----
__global__ void k_convert_w(const float* __restrict__ W, u16* __restrict__ wt) {
  int g = blockIdx.x * blockDim.x + threadIdx.x;   // 0 .. 131071
  int n = g & 255, k = g >> 8;
  wt[n * D_IN + k] = f2bf(W[k * D_OUT + n]);
}

// ---- histogram of edge_dst ----
__global__ void k_hist(const int* __restrict__ edst, int* __restrict__ counts, int E) {
  int e = blockIdx.x * blockDim.x + threadIdx.x;
  if (e < E) atomicAdd(&counts[edst[e]], 1);
}

// ---- hierarchical scan: phase 1 — per-block inclusive scan (256 elems/block)
__global__ void k_scan1(const int* __restrict__ counts, int* __restrict__ row_start,
                        int* __restrict__ btot, int n) {
  __shared__ int buf[256];
  int t = threadIdx.x;
  int i = blockIdx.x * 256 + t;
  int c = (i < n) ? counts[i] : 0;
  buf[t] = c;
  __syncthreads();
#pragma unroll
  for (int off = 1; off < 256; off <<= 1) {
    int v = (t >= off) ? buf[t - off] : 0;
    __syncthreads();
    buf[t] += v;
    __syncthreads();
  }
  if (i < n) row_start[i + 1] = buf[t];           // block-local inclusive
  if (t == 255) btot[blockIdx.x] = buf[255];      // block total
}

// ---- phase 2 — single small block scans block totals (exclusive, in place)
__global__ void k_scan2(int* __restrict__ btot, int nb) {
  __shared__ int buf[256];
  int t = threadIdx.x;
  int c = (t < nb) ? btot[t] : 0;
  buf[t] = c;
  __syncthreads();
#pragma unroll
  for (int off = 1; off < 256; off <<= 1) {
    int v = (t >= off) ? buf[t - off] : 0;
    __syncthreads();
    buf[t] += v;
    __syncthreads();
  }
  if (t < nb) btot[t] = buf[t] - c;               // exclusive
}

// ---- phase 3 — add block offsets, produce row_start and cursor
__global__ void k_scan3(const int* __restrict__ counts, int* __restrict__ row_start,
                        int* __restrict__ cursor, const int* __restrict__ btot, int n) {
  int i = blockIdx.x * blockDim.x + threadIdx.x;
  if (i < n) {
    int v = row_start[i + 1] + btot[i >> 8];
    row_start[i + 1] = v;
    cursor[i] = v - counts[i];
  }
  if (i == 0) row_start[0] = 0;
}

// ---- scatter edges into CSR buckets, packed {src, val} ----
__global__ void k_scatter(const int* __restrict__ esrc, const int* __restrict__ edst,
                          const float* __restrict__ ev, int* __restrict__ cursor,
                          int2* __restrict__ pack, int E) {
  int e = blockIdx.x * blockDim.x + threadIdx.x;
  if (e < E) {
    int d = edst[e];
    int pos = atomicAdd(&cursor[d], 1);
    pack[pos] = make_int2(esrc[e], __float_as_int(ev[e]));
  }
}

// ---- MFMA GEMM: hb[M=50000][256] (bf16) = xb[M_PAD][512] @ Wt^T ----
__global__ __launch_bounds__(256) void k_gemm(const u16* __restrict__ A,   // [M_PAD][512]
                                              const u16* __restrict__ Bt,  // [256][512]
                                              u16* __restrict__ C,         // [50000][256]
                                              int M) {
  __shared__ u16 As[128 * 64];
  __shared__ u16 Bs[128 * 64];
  int tid  = threadIdx.x;
  int wave = tid >> 6, lane = tid & 63;
  int bm = blockIdx.x >> 1, bn = blockIdx.x & 1;
  int m0 = bm * 128, n0 = bn * 128;
  int wr = wave >> 1, wc = wave & 1;
  int r = lane & 15, q = lane >> 4;

  f32x4 acc[4][4];
#pragma unroll
  for (int i = 0; i < 4; ++i)
#pragma unroll
    for (int j = 0; j < 4; ++j) acc[i][j] = (f32x4){0.f, 0.f, 0.f, 0.f};

  for (int k0 = 0; k0 < D_IN; k0 += 64) {
#pragma unroll
    for (int j = 0; j < 4; ++j) {
      int c = tid + j * 256;          // 16B chunk id, 0..1023
      int row = c >> 3, kc = c & 7;   // 8 chunks per 64-elem row
      gload_lds16(A  + (size_t)(m0 + row) * D_IN + k0 + kc * 8, As + c * 8);
      gload_lds16(Bt + (size_t)(n0 + row) * D_IN + k0 + kc * 8, Bs + c * 8);
    }
    __syncthreads();
#pragma unroll
    for (int kk = 0; kk < 2; ++kk) {
      bf16x8 a[4], b[4];
#pragma unroll
      for (int i = 0; i < 4; ++i)
        a[i] = *(const bf16x8*)(As + (wr * 64 + i * 16 + r) * 64 + kk * 32 + q * 8);
#pragma unroll
      for (int j = 0; j < 4; ++j)
        b[j] = *(const bf16x8*)(Bs + (wc * 64 + j * 16 + r) * 64 + kk * 32 + q * 8);
#pragma unroll
      for (int i = 0; i < 4; ++i)
#pragma unroll
        for (int j = 0; j < 4; ++j)
          acc[i][j] = __builtin_amdgcn_mfma_f32_16x16x32_bf16(a[i], b[j], acc[i][j], 0, 0, 0);
    }
    __syncthreads();
  }

#pragma unroll
  for (int i = 0; i < 4; ++i)
#pragma unroll
    for (int j = 0; j < 4; ++j)
#pragma unroll
      for (int t2 = 0; t2 < 4; ++t2) {
        int row = m0 + wr * 64 + i * 16 + q * 4 + t2;
        int col = n0 + wc * 64 + j * 16 + r;
        if (row < M) C[(size_t)row * D_OUT + col] = f2bf(acc[i][j][t2]);
      }
}

// ---- aggregation: one wave per dst node; wave-uniform edge records loaded
// ---- directly (same-address 8B loads, L1-resident), 16 gathers in flight ----
__global__ __launch_bounds__(256) void k_agg(
    const u16* __restrict__ hb, const int* __restrict__ row_start,
    const int2* __restrict__ pack, float* __restrict__ out, int n_nodes) {
  int wave = threadIdx.x >> 6, lane = threadIdx.x & 63;
  int node = blockIdx.x * 4 + wave;
  if (node >= n_nodes) return;
  int s0 = row_start[node], s1 = row_start[node + 1];
  int cnt = s1 - s0;
  const int2* __restrict__ p = pack + s0;

  f32x4 a0 = {0.f,0.f,0.f,0.f}, a1 = {0.f,0.f,0.f,0.f};
  f32x4 a2 = {0.f,0.f,0.f,0.f}, a3 = {0.f,0.f,0.f,0.f};
  size_t lane8 = (size_t)lane * 8;   // byte offset within an h row (u16x4)

  int e = 0;
  for (; e + 16 <= cnt; e += 16) {
    int2 q[16];
#pragma unroll
    for (int j = 0; j < 16; ++j) q[j] = p[e + j];     // wave-uniform 8B loads
    u16x4 h[16];
#pragma unroll
    for (int j = 0; j < 16; ++j)
      h[j] = __builtin_nontemporal_load(
          (const u16x4*)((const char*)hb + (((size_t)(u32)q[j].x) << 9) + lane8));
#pragma unroll
    for (int j = 0; j < 16; ++j) {
      float v = __int_as_float(q[j].y);
      f32x4* a = (j & 2) ? ((j & 1) ? &a3 : &a2) : ((j & 1) ? &a1 : &a0);
      (*a)[0] += v * bf2f(h[j][0]);
      (*a)[1] += v * bf2f(h[j][1]);
      (*a)[2] += v * bf2f(h[j][2]);
      (*a)[3] += v * bf2f(h[j][3]);
    }
  }
  for (; e + 4 <= cnt; e += 4) {
    int2 q[4];
#pragma unroll
    for (int j = 0; j < 4; ++j) q[j] = p[e + j];
    u16x4 h[4];
#pragma unroll
    for (int j = 0; j < 4; ++j)
      h[j] = __builtin_nontemporal_load(
          (const u16x4*)((const char*)hb + (((size_t)(u32)q[j].x) << 9) + lane8));
#pragma unroll
    for (int j = 0; j < 4; ++j) {
      float v = __int_as_float(q[j].y);
      f32x4* a = (j & 2) ? ((j & 1) ? &a3 : &a2) : ((j & 1) ? &a1 : &a0);
      (*a)[0] += v * bf2f(h[j][0]);
      (*a)[1] += v * bf2f(h[j][1]);
      (*a)[2] += v * bf2f(h[j][2]);
      (*a)[3] += v * bf2f(h[j][3]);
    }
  }
  for (; e < cnt; ++e) {
    int2 q = p[e];
    float v = __int_as_float(q.y);
    u16x4 h = __builtin_nontemporal_load(
        (const u16x4*)((const char*)hb + (((size_t)(u32)q.x) << 9) + lane8));
    a0[0] += v * bf2f(h[0]);
    a0[1] += v * bf2f(h[1]);
    a0[2] += v * bf2f(h[2]);
    a0[3] += v * bf2f(h[3]);
  }

  float4 o;
  o.x = fmaxf(a0[0] + a1[0] + a2[0] + a3[0], 0.f);
  o.y = fmaxf(a0[1] + a1[1] + a2[1] + a3[1], 0.f);
  o.z = fmaxf(a0[2] + a1[2] + a2[2] + a3[2], 0.f);
  o.w = fmaxf(a0[3] + a1[3] + a2[3] + a3[3], 0.f);
  *(float4*)(out + (size_t)node * D_OUT + lane * 4) = o;
}

extern "C" void kernel_launch(void* const* d_in, const int* in_sizes, int n_in,
                              void* d_out, int out_size, void* d_ws, size_t ws_size,
                              hipStream_t stream) {
  const float* x    = (const float*)d_in[0];
  const float* W    = (const float*)d_in[1];
  const float* ev   = (const float*)d_in[2];
  const int*   esrc = (const int*)d_in[3];
  const int*   edst = (const int*)d_in[4];
  float* out = (float*)d_out;

  char* ws = (char*)d_ws;
  size_t off = 0;
  auto alloc = [&](size_t bytes) -> void* {
    off = (off + 255) & ~(size_t)255;
    void* p = ws + off;
    off += bytes;
    return p;
  };
  u16*   xb        = (u16*)  alloc((size_t)M_PAD * D_IN * 2);
  u16*   wt        = (u16*)  alloc((size_t)D_OUT * D_IN * 2);
  u16*   hb        = (u16*)  alloc((size_t)N_NODES * D_OUT * 2);
  int*   counts    = (int*)  alloc((size_t)N_NODES * 4);
  int*   row_start = (int*)  alloc((size_t)(N_NODES + 1) * 4);
  int*   cursor    = (int*)  alloc((size_t)N_NODES * 4);
  int*   btot      = (int*)  alloc(256 * 4);
  int2*  pack      = (int2*) alloc((size_t)N_EDGES * 8);

  long n_valid = (long)N_NODES * D_IN;        // 25,600,000 (mult of 8)
  long n_total = (long)M_PAD * D_IN;          // 25,624,576 (mult of 8)
  int nb = (N_NODES + 255) / 256;             // 196 scan blocks

  k_zero<<<nb, 256, 0, stream>>>(counts, N_NODES);
  k_convert_x<<<(int)(n_total / 8 / 256), 256, 0, stream>>>(x, xb, n_valid, n_total);
  k_convert_w<<<(D_IN * D_OUT) / 256, 256, 0, stream>>>(W, wt);
  k_hist<<<N_EDGES / 256, 256, 0, stream>>>(edst, counts, N_EDGES);
  k_scan1<<<nb, 256, 0, stream>>>(counts, row_start, btot, N_NODES);
  k_scan2<<<1, 256, 0, stream>>>(btot, nb);
  k_scan3<<<nb, 256, 0, stream>>>(counts, row_start, cursor, btot, N_NODES);
  k_scatter<<<N_EDGES / 256, 256, 0, stream>>>(esrc, edst, ev, cursor, pack, N_EDGES);
  k_gemm<<<(M_PAD / 128) * (D_OUT / 128), 256, 0, stream>>>(xb, wt, hb, N_NODES);
  k_agg<<<(N_NODES + 3) / 4, 256, 0, stream>>>(hb, row_start, pack, out, N_NODES);
}

// Round 5
// 217.295 us; speedup vs baseline: 1.1463x; 1.1463x over previous
//
#include <hip/hip_runtime.h>

typedef unsigned short u16;
typedef unsigned int   u32;
typedef __attribute__((ext_vector_type(8))) short bf16x8;
typedef __attribute__((ext_vector_type(4))) float f32x4;
typedef __attribute__((ext_vector_type(4))) unsigned short u16x4;

#define N_NODES 50000
#define N_EDGES 800000
#define D_IN    512
#define D_OUT   256
#define M_PAD   50048   // 391 * 128

__device__ __forceinline__ u16 f2bf(float f) {
  u32 u = __float_as_uint(f);
  return (u16)((u + 0x7FFFu + ((u >> 16) & 1u)) >> 16);  // RNE
}
__device__ __forceinline__ float bf2f(u16 h) {
  return __uint_as_float(((u32)h) << 16);
}

__device__ __forceinline__ void gload_lds16(const void* g, void* l) {
  __builtin_amdgcn_global_load_lds(
      (const __attribute__((address_space(1))) unsigned int*)g,
      (__attribute__((address_space(3))) unsigned int*)l, 16, 0, 0);
}

// ---- zero the counts array (replaces 60us rocclr fillBuffer) ----
__global__ void k_zero(int* __restrict__ c, int n) {
  int i = blockIdx.x * blockDim.x + threadIdx.x;
  if (i < n) c[i] = 0;
}

// ---- x (fp32) -> xb (bf16), zero-pad rows [N_NODES, M_PAD) ----
__global__ void k_convert_x(const float* __restrict__ x, u16* __restrict__ xb,
                            long n_valid, long n_total) {
  long i = ((long)blockIdx.x * blockDim.x + threadIdx.x) * 8;
  if (i >= n_total) return;
  uint4 o;
  if (i < n_valid) {
    float4 f0 = *(const float4*)(x + i);
    float4 f1 = *(const float4*)(x + i + 4);
    o.x = (u32)f2bf(f0.x) | ((u32)f2bf(f0.y) << 16);
    o.y = (u32)f2bf(f0.z) | ((u32)f2bf(f0.w) << 16);
    o.z = (u32)f2bf(f1.x) | ((u32)f2bf(f1.y) << 16);
    o.w = (u32)f2bf(f1.z) | ((u32)f2bf(f1.w) << 16);
  } else {
    o.x = o.y = o.z = o.w = 0u;
  }
  *(uint4*)(xb + i) = o;
}

// ---- W [K=512][N=256] fp32 -> Wt [N=256][K=512] bf16 ----
__global__ void k_convert_w(const float* __restrict__ W, u16* __restrict__ wt) {
  int g = blockIdx.x * blockDim.x + threadIdx.x;   // 0 .. 131071
  int n = g & 255, k = g >> 8;
  wt[n * D_IN + k] = f2bf(W[k * D_OUT + n]);
}

// ---- histogram of edge_dst ----
__global__ void k_hist(const int* __restrict__ edst, int* __restrict__ counts, int E) {
  int e = blockIdx.x * blockDim.x + threadIdx.x;
  if (e < E) atomicAdd(&counts[edst[e]], 1);
}

// ---- hierarchical scan: phase 1 — per-block inclusive scan (256 elems/block)
__global__ void k_scan1(const int* __restrict__ counts, int* __restrict__ row_start,
                        int* __restrict__ btot, int n) {
  __shared__ int buf[256];
  int t = threadIdx.x;
  int i = blockIdx.x * 256 + t;
  int c = (i < n) ? counts[i] : 0;
  buf[t] = c;
  __syncthreads();
#pragma unroll
  for (int off = 1; off < 256; off <<= 1) {
    int v = (t >= off) ? buf[t - off] : 0;
    __syncthreads();
    buf[t] += v;
    __syncthreads();
  }
  if (i < n) row_start[i + 1] = buf[t];           // block-local inclusive
  if (t == 255) btot[blockIdx.x] = buf[255];      // block total
}

// ---- phase 2 — single small block scans block totals (exclusive, in place)
__global__ void k_scan2(int* __restrict__ btot, int nb) {
  __shared__ int buf[256];
  int t = threadIdx.x;
  int c = (t < nb) ? btot[t] : 0;
  buf[t] = c;
  __syncthreads();
#pragma unroll
  for (int off = 1; off < 256; off <<= 1) {
    int v = (t >= off) ? buf[t - off] : 0;
    __syncthreads();
    buf[t] += v;
    __syncthreads();
  }
  if (t < nb) btot[t] = buf[t] - c;               // exclusive
}

// ---- phase 3 — add block offsets, produce row_start and cursor
__global__ void k_scan3(const int* __restrict__ counts, int* __restrict__ row_start,
                        int* __restrict__ cursor, const int* __restrict__ btot, int n) {
  int i = blockIdx.x * blockDim.x + threadIdx.x;
  if (i < n) {
    int v = row_start[i + 1] + btot[i >> 8];
    row_start[i + 1] = v;
    cursor[i] = v - counts[i];
  }
  if (i == 0) row_start[0] = 0;
}

// ---- scatter edges into CSR buckets, packed {src, val} ----
__global__ void k_scatter(const int* __restrict__ esrc, const int* __restrict__ edst,
                          const float* __restrict__ ev, int* __restrict__ cursor,
                          int2* __restrict__ pack, int E) {
  int e = blockIdx.x * blockDim.x + threadIdx.x;
  if (e < E) {
    int d = edst[e];
    int pos = atomicAdd(&cursor[d], 1);
    pack[pos] = make_int2(esrc[e], __float_as_int(ev[e]));
  }
}

// ---- MFMA GEMM: hb[M=50000][256] (bf16) = xb[M_PAD][512] @ Wt^T ----
__global__ __launch_bounds__(256) void k_gemm(const u16* __restrict__ A,   // [M_PAD][512]
                                              const u16* __restrict__ Bt,  // [256][512]
                                              u16* __restrict__ C,         // [50000][256]
                                              int M) {
  __shared__ u16 As[128 * 64];
  __shared__ u16 Bs[128 * 64];
  int tid  = threadIdx.x;
  int wave = tid >> 6, lane = tid & 63;
  int bm = blockIdx.x >> 1, bn = blockIdx.x & 1;
  int m0 = bm * 128, n0 = bn * 128;
  int wr = wave >> 1, wc = wave & 1;
  int r = lane & 15, q = lane >> 4;

  f32x4 acc[4][4];
#pragma unroll
  for (int i = 0; i < 4; ++i)
#pragma unroll
    for (int j = 0; j < 4; ++j) acc[i][j] = (f32x4){0.f, 0.f, 0.f, 0.f};

  for (int k0 = 0; k0 < D_IN; k0 += 64) {
#pragma unroll
    for (int j = 0; j < 4; ++j) {
      int c = tid + j * 256;          // 16B chunk id, 0..1023
      int row = c >> 3, kc = c & 7;   // 8 chunks per 64-elem row
      gload_lds16(A  + (size_t)(m0 + row) * D_IN + k0 + kc * 8, As + c * 8);
      gload_lds16(Bt + (size_t)(n0 + row) * D_IN + k0 + kc * 8, Bs + c * 8);
    }
    __syncthreads();
#pragma unroll
    for (int kk = 0; kk < 2; ++kk) {
      bf16x8 a[4], b[4];
#pragma unroll
      for (int i = 0; i < 4; ++i)
        a[i] = *(const bf16x8*)(As + (wr * 64 + i * 16 + r) * 64 + kk * 32 + q * 8);
#pragma unroll
      for (int j = 0; j < 4; ++j)
        b[j] = *(const bf16x8*)(Bs + (wc * 64 + j * 16 + r) * 64 + kk * 32 + q * 8);
#pragma unroll
      for (int i = 0; i < 4; ++i)
#pragma unroll
        for (int j = 0; j < 4; ++j)
          acc[i][j] = __builtin_amdgcn_mfma_f32_16x16x32_bf16(a[i], b[j], acc[i][j], 0, 0, 0);
    }
    __syncthreads();
  }

#pragma unroll
  for (int i = 0; i < 4; ++i)
#pragma unroll
    for (int j = 0; j < 4; ++j)
#pragma unroll
      for (int t2 = 0; t2 < 4; ++t2) {
        int row = m0 + wr * 64 + i * 16 + q * 4 + t2;
        int col = n0 + wc * 64 + j * 16 + r;
        if (row < M) C[(size_t)row * D_OUT + col] = f2bf(acc[i][j][t2]);
      }
}

// ---- aggregation: one wave per dst node; lane-parallel coalesced CSR load,
// ---- shfl broadcast, 16 cached gathers in flight ----
__global__ __launch_bounds__(256) void k_agg(
    const u16* __restrict__ hb, const int* __restrict__ row_start,
    const int2* __restrict__ pack, float* __restrict__ out, int n_nodes) {
  int wave = threadIdx.x >> 6, lane = threadIdx.x & 63;
  int node = blockIdx.x * 4 + wave;
  if (node >= n_nodes) return;
  int s0 = row_start[node], s1 = row_start[node + 1];
  int cnt = s1 - s0;

  f32x4 a0 = {0.f,0.f,0.f,0.f}, a1 = {0.f,0.f,0.f,0.f};
  f32x4 a2 = {0.f,0.f,0.f,0.f}, a3 = {0.f,0.f,0.f,0.f};
  size_t lane8 = (size_t)lane * 8;   // byte offset within an h row

  for (int base = 0; base < cnt; base += 64) {
    int m = cnt - base; if (m > 64) m = 64;
    // coalesced per-lane load of this chunk's {src, val}
    int   msrc = 0;
    float mval = 0.f;
    if (lane < m) {
      int2 p = pack[s0 + base + lane];
      msrc = p.x;
      mval = __uint_as_float((u32)p.y);
    }
    int k = 0;
    for (; k + 16 <= m; k += 16) {
      int   s[16];
      float v[16];
#pragma unroll
      for (int j = 0; j < 16; ++j) {
        s[j] = __shfl(msrc, k + j);
        v[j] = __shfl(mval, k + j);
      }
      u16x4 h[16];
#pragma unroll
      for (int j = 0; j < 16; ++j)
        h[j] = *(const u16x4*)((const char*)hb + (((size_t)(u32)s[j]) << 9) + lane8);
#pragma unroll
      for (int j = 0; j < 16; ++j) {
        f32x4* a = (j & 2) ? ((j & 1) ? &a3 : &a2) : ((j & 1) ? &a1 : &a0);
        (*a)[0] += v[j] * bf2f(h[j][0]);
        (*a)[1] += v[j] * bf2f(h[j][1]);
        (*a)[2] += v[j] * bf2f(h[j][2]);
        (*a)[3] += v[j] * bf2f(h[j][3]);
      }
    }
    for (; k + 4 <= m; k += 4) {
      int   s[4];
      float v[4];
#pragma unroll
      for (int j = 0; j < 4; ++j) {
        s[j] = __shfl(msrc, k + j);
        v[j] = __shfl(mval, k + j);
      }
      u16x4 h[4];
#pragma unroll
      for (int j = 0; j < 4; ++j)
        h[j] = *(const u16x4*)((const char*)hb + (((size_t)(u32)s[j]) << 9) + lane8);
#pragma unroll
      for (int j = 0; j < 4; ++j) {
        f32x4* a = (j & 1) ? &a1 : &a0;
        (*a)[0] += v[j] * bf2f(h[j][0]);
        (*a)[1] += v[j] * bf2f(h[j][1]);
        (*a)[2] += v[j] * bf2f(h[j][2]);
        (*a)[3] += v[j] * bf2f(h[j][3]);
      }
    }
    for (; k < m; ++k) {
      int   s = __shfl(msrc, k);
      float v = __shfl(mval, k);
      u16x4 h = *(const u16x4*)((const char*)hb + (((size_t)(u32)s) << 9) + lane8);
      a0[0] += v * bf2f(h[0]);
      a0[1] += v * bf2f(h[1]);
      a0[2] += v * bf2f(h[2]);
      a0[3] += v * bf2f(h[3]);
    }
  }
  float4 o;
  o.x = fmaxf(a0[0] + a1[0] + a2[0] + a3[0], 0.f);
  o.y = fmaxf(a0[1] + a1[1] + a2[1] + a3[1], 0.f);
  o.z = fmaxf(a0[2] + a1[2] + a2[2] + a3[2], 0.f);
  o.w = fmaxf(a0[3] + a1[3] + a2[3] + a3[3], 0.f);
  *(float4*)(out + (size_t)node * D_OUT + lane * 4) = o;
}

extern "C" void kernel_launch(void* const* d_in, const int* in_sizes, int n_in,
                              void* d_out, int out_size, void* d_ws, size_t ws_size,
                              hipStream_t stream) {
  const float* x    = (const float*)d_in[0];
  const float* W    = (const float*)d_in[1];
  const float* ev   = (const float*)d_in[2];
  const int*   esrc = (const int*)d_in[3];
  const int*   edst = (const int*)d_in[4];
  float* out = (float*)d_out;

  char* ws = (char*)d_ws;
  size_t off = 0;
  auto alloc = [&](size_t bytes) -> void* {
    off = (off + 255) & ~(size_t)255;
    void* p = ws + off;
    off += bytes;
    return p;
  };
  u16*   xb        = (u16*)  alloc((size_t)M_PAD * D_IN * 2);
  u16*   wt        = (u16*)  alloc((size_t)D_OUT * D_IN * 2);
  u16*   hb        = (u16*)  alloc((size_t)N_NODES * D_OUT * 2);
  int*   counts    = (int*)  alloc((size_t)N_NODES * 4);
  int*   row_start = (int*)  alloc((size_t)(N_NODES + 1) * 4);
  int*   cursor    = (int*)  alloc((size_t)N_NODES * 4);
  int*   btot      = (int*)  alloc(256 * 4);
  int2*  pack      = (int2*) alloc((size_t)N_EDGES * 8);

  long n_valid = (long)N_NODES * D_IN;        // 25,600,000 (mult of 8)
  long n_total = (long)M_PAD * D_IN;          // 25,624,576 (mult of 8)
  int nb = (N_NODES + 255) / 256;             // 196 scan blocks

  k_zero<<<nb, 256, 0, stream>>>(counts, N_NODES);
  k_convert_x<<<(int)(n_total / 8 / 256), 256, 0, stream>>>(x, xb, n_valid, n_total);
  k_convert_w<<<(D_IN * D_OUT) / 256, 256, 0, stream>>>(W, wt);
  k_hist<<<N_EDGES / 256, 256, 0, stream>>>(edst, counts, N_EDGES);
  k_scan1<<<nb, 256, 0, stream>>>(counts, row_start, btot, N_NODES);
  k_scan2<<<1, 256, 0, stream>>>(btot, nb);
  k_scan3<<<nb, 256, 0, stream>>>(counts, row_start, cursor, btot, N_NODES);
  k_scatter<<<N_EDGES / 256, 256, 0, stream>>>(esrc, edst, ev, cursor, pack, N_EDGES);
  k_gemm<<<(M_PAD / 128) * (D_OUT / 128), 256, 0, stream>>>(xb, wt, hb, N_NODES);
  k_agg<<<(N_NODES + 3) / 4, 256, 0, stream>>>(hb, row_start, pack, out, N_NODES);
}

// Round 6
// 179.323 us; speedup vs baseline: 1.3891x; 1.2117x over previous
//
#include <hip/hip_runtime.h>

typedef unsigned short u16;
typedef unsigned int   u32;
typedef __attribute__((ext_vector_type(8))) short bf16x8;
typedef __attribute__((ext_vector_type(4))) float f32x4;
typedef __attribute__((ext_vector_type(4))) unsigned short u16x4;

#define N_NODES 50000
#define N_EDGES 800000
#define D_IN    512
#define D_OUT   256
#define M_PAD   50048   // 391 * 128

__device__ __forceinline__ u16 f2bf(float f) {
  u32 u = __float_as_uint(f);
  return (u16)((u + 0x7FFFu + ((u >> 16) & 1u)) >> 16);  // RNE
}
__device__ __forceinline__ float bf2f(u16 h) {
  return __uint_as_float(((u32)h) << 16);
}

__device__ __forceinline__ void gload_lds16(const void* g, void* l) {
  __builtin_amdgcn_global_load_lds(
      (const __attribute__((address_space(1))) unsigned int*)g,
      (__attribute__((address_space(3))) unsigned int*)l, 16, 0, 0);
}

// ---- zero the counts array (replaces 60us rocclr fillBuffer) ----
__global__ void k_zero(int* __restrict__ c, int n) {
  int i = blockIdx.x * blockDim.x + threadIdx.x;
  if (i < n) c[i] = 0;
}

// ---- x (fp32) -> xb (bf16), zero-pad rows [N_NODES, M_PAD) ----
__global__ void k_convert_x(const float* __restrict__ x, u16* __restrict__ xb,
                            long n_valid, long n_total) {
  long i = ((long)blockIdx.x * blockDim.x + threadIdx.x) * 8;
  if (i >= n_total) return;
  uint4 o;
  if (i < n_valid) {
    float4 f0 = *(const float4*)(x + i);
    float4 f1 = *(const float4*)(x + i + 4);
    o.x = (u32)f2bf(f0.x) | ((u32)f2bf(f0.y) << 16);
    o.y = (u32)f2bf(f0.z) | ((u32)f2bf(f0.w) << 16);
    o.z = (u32)f2bf(f1.x) | ((u32)f2bf(f1.y) << 16);
    o.w = (u32)f2bf(f1.z) | ((u32)f2bf(f1.w) << 16);
  } else {
    o.x = o.y = o.z = o.w = 0u;
  }
  *(uint4*)(xb + i) = o;
}

// ---- W [K=512][N=256] fp32 -> Wt [N=256][K=512] bf16 ----
__global__ void k_convert_w(const float* __restrict__ W, u16* __restrict__ wt) {
  int g = blockIdx.x * blockDim.x + threadIdx.x;   // 0 .. 131071
  int n = g & 255, k = g >> 8;
  wt[n * D_IN + k] = f2bf(W[k * D_OUT + n]);
}

// ---- histogram of edge_dst + per-edge rank (the ONLY atomic pass) ----
__global__ void k_hist(const int* __restrict__ edst, int* __restrict__ counts,
                       int* __restrict__ rank, int E) {
  int e = blockIdx.x * blockDim.x + threadIdx.x;
  if (e < E) rank[e] = atomicAdd(&counts[edst[e]], 1);
}

// ---- hierarchical scan: phase 1 — per-block inclusive scan (256 elems/block)
__global__ void k_scan1(const int* __restrict__ counts, int* __restrict__ row_start,
                        int* __restrict__ btot, int n) {
  __shared__ int buf[256];
  int t = threadIdx.x;
  int i = blockIdx.x * 256 + t;
  int c = (i < n) ? counts[i] : 0;
  buf[t] = c;
  __syncthreads();
#pragma unroll
  for (int off = 1; off < 256; off <<= 1) {
    int v = (t >= off) ? buf[t - off] : 0;
    __syncthreads();
    buf[t] += v;
    __syncthreads();
  }
  if (i < n) row_start[i + 1] = buf[t];           // block-local inclusive
  if (t == 255) btot[blockIdx.x] = buf[255];      // block total
}

// ---- phase 2 — single small block scans block totals (exclusive, in place)
__global__ void k_scan2(int* __restrict__ btot, int nb) {
  __shared__ int buf[256];
  int t = threadIdx.x;
  int c = (t < nb) ? btot[t] : 0;
  buf[t] = c;
  __syncthreads();
#pragma unroll
  for (int off = 1; off < 256; off <<= 1) {
    int v = (t >= off) ? buf[t - off] : 0;
    __syncthreads();
    buf[t] += v;
    __syncthreads();
  }
  if (t < nb) btot[t] = buf[t] - c;               // exclusive
}

// ---- phase 3 — add block offsets; row_start[d] = exclusive prefix ----
__global__ void k_scan3(const int* __restrict__ counts, int* __restrict__ row_start,
                        const int* __restrict__ btot, int n) {
  int i = blockIdx.x * blockDim.x + threadIdx.x;
  if (i < n) row_start[i + 1] += btot[i >> 8];
  if (i == 0) row_start[0] = 0;
}

// ---- scatter edges into CSR buckets — NO atomics ----
__global__ void k_scatter(const int* __restrict__ esrc, const int* __restrict__ edst,
                          const float* __restrict__ ev, const int* __restrict__ row_start,
                          const int* __restrict__ rank,
                          int2* __restrict__ pack, int E) {
  int e = blockIdx.x * blockDim.x + threadIdx.x;
  if (e < E) {
    int pos = row_start[edst[e]] + rank[e];
    pack[pos] = make_int2(esrc[e], __float_as_int(ev[e]));
  }
}

// ---- MFMA GEMM: hb[M=50000][256] (bf16) = xb[M_PAD][512] @ Wt^T ----
__global__ __launch_bounds__(256) void k_gemm(const u16* __restrict__ A,   // [M_PAD][512]
                                              const u16* __restrict__ Bt,  // [256][512]
                                              u16* __restrict__ C,         // [50000][256]
                                              int M) {
  __shared__ u16 As[128 * 64];
  __shared__ u16 Bs[128 * 64];
  int tid  = threadIdx.x;
  int wave = tid >> 6, lane = tid & 63;
  int bm = blockIdx.x >> 1, bn = blockIdx.x & 1;
  int m0 = bm * 128, n0 = bn * 128;
  int wr = wave >> 1, wc = wave & 1;
  int r = lane & 15, q = lane >> 4;

  f32x4 acc[4][4];
#pragma unroll
  for (int i = 0; i < 4; ++i)
#pragma unroll
    for (int j = 0; j < 4; ++j) acc[i][j] = (f32x4){0.f, 0.f, 0.f, 0.f};

  for (int k0 = 0; k0 < D_IN; k0 += 64) {
#pragma unroll
    for (int j = 0; j < 4; ++j) {
      int c = tid + j * 256;          // 16B chunk id, 0..1023
      int row = c >> 3, kc = c & 7;   // 8 chunks per 64-elem row
      gload_lds16(A  + (size_t)(m0 + row) * D_IN + k0 + kc * 8, As + c * 8);
      gload_lds16(Bt + (size_t)(n0 + row) * D_IN + k0 + kc * 8, Bs + c * 8);
    }
    __syncthreads();
#pragma unroll
    for (int kk = 0; kk < 2; ++kk) {
      bf16x8 a[4], b[4];
#pragma unroll
      for (int i = 0; i < 4; ++i)
        a[i] = *(const bf16x8*)(As + (wr * 64 + i * 16 + r) * 64 + kk * 32 + q * 8);
#pragma unroll
      for (int j = 0; j < 4; ++j)
        b[j] = *(const bf16x8*)(Bs + (wc * 64 + j * 16 + r) * 64 + kk * 32 + q * 8);
#pragma unroll
      for (int i = 0; i < 4; ++i)
#pragma unroll
        for (int j = 0; j < 4; ++j)
          acc[i][j] = __builtin_amdgcn_mfma_f32_16x16x32_bf16(a[i], b[j], acc[i][j], 0, 0, 0);
    }
    __syncthreads();
  }

#pragma unroll
  for (int i = 0; i < 4; ++i)
#pragma unroll
    for (int j = 0; j < 4; ++j)
#pragma unroll
      for (int t2 = 0; t2 < 4; ++t2) {
        int row = m0 + wr * 64 + i * 16 + q * 4 + t2;
        int col = n0 + wc * 64 + j * 16 + r;
        if (row < M) C[(size_t)row * D_OUT + col] = f2bf(acc[i][j][t2]);
      }
}

// ---- aggregation: one wave per dst node; lane-parallel coalesced CSR load,
// ---- shfl broadcast, 16 cached gathers in flight ----
__global__ __launch_bounds__(256) void k_agg(
    const u16* __restrict__ hb, const int* __restrict__ row_start,
    const int2* __restrict__ pack, float* __restrict__ out, int n_nodes) {
  int wave = threadIdx.x >> 6, lane = threadIdx.x & 63;
  int node = blockIdx.x * 4 + wave;
  if (node >= n_nodes) return;
  int s0 = row_start[node], s1 = row_start[node + 1];
  int cnt = s1 - s0;

  f32x4 a0 = {0.f,0.f,0.f,0.f}, a1 = {0.f,0.f,0.f,0.f};
  f32x4 a2 = {0.f,0.f,0.f,0.f}, a3 = {0.f,0.f,0.f,0.f};
  size_t lane8 = (size_t)lane * 8;   // byte offset within an h row

  for (int base = 0; base < cnt; base += 64) {
    int m = cnt - base; if (m > 64) m = 64;
    // coalesced per-lane load of this chunk's {src, val}
    int   msrc = 0;
    float mval = 0.f;
    if (lane < m) {
      int2 p = pack[s0 + base + lane];
      msrc = p.x;
      mval = __uint_as_float((u32)p.y);
    }
    int k = 0;
    for (; k + 16 <= m; k += 16) {
      int   s[16];
      float v[16];
#pragma unroll
      for (int j = 0; j < 16; ++j) {
        s[j] = __shfl(msrc, k + j);
        v[j] = __shfl(mval, k + j);
      }
      u16x4 h[16];
#pragma unroll
      for (int j = 0; j < 16; ++j)
        h[j] = *(const u16x4*)((const char*)hb + (((size_t)(u32)s[j]) << 9) + lane8);
#pragma unroll
      for (int j = 0; j < 16; ++j) {
        f32x4* a = (j & 2) ? ((j & 1) ? &a3 : &a2) : ((j & 1) ? &a1 : &a0);
        (*a)[0] += v[j] * bf2f(h[j][0]);
        (*a)[1] += v[j] * bf2f(h[j][1]);
        (*a)[2] += v[j] * bf2f(h[j][2]);
        (*a)[3] += v[j] * bf2f(h[j][3]);
      }
    }
    for (; k + 4 <= m; k += 4) {
      int   s[4];
      float v[4];
#pragma unroll
      for (int j = 0; j < 4; ++j) {
        s[j] = __shfl(msrc, k + j);
        v[j] = __shfl(mval, k + j);
      }
      u16x4 h[4];
#pragma unroll
      for (int j = 0; j < 4; ++j)
        h[j] = *(const u16x4*)((const char*)hb + (((size_t)(u32)s[j]) << 9) + lane8);
#pragma unroll
      for (int j = 0; j < 4; ++j) {
        f32x4* a = (j & 1) ? &a1 : &a0;
        (*a)[0] += v[j] * bf2f(h[j][0]);
        (*a)[1] += v[j] * bf2f(h[j][1]);
        (*a)[2] += v[j] * bf2f(h[j][2]);
        (*a)[3] += v[j] * bf2f(h[j][3]);
      }
    }
    for (; k < m; ++k) {
      int   s = __shfl(msrc, k);
      float v = __shfl(mval, k);
      u16x4 h = *(const u16x4*)((const char*)hb + (((size_t)(u32)s) << 9) + lane8);
      a0[0] += v * bf2f(h[0]);
      a0[1] += v * bf2f(h[1]);
      a0[2] += v * bf2f(h[2]);
      a0[3] += v * bf2f(h[3]);
    }
  }
  float4 o;
  o.x = fmaxf(a0[0] + a1[0] + a2[0] + a3[0], 0.f);
  o.y = fmaxf(a0[1] + a1[1] + a2[1] + a3[1], 0.f);
  o.z = fmaxf(a0[2] + a1[2] + a2[2] + a3[2], 0.f);
  o.w = fmaxf(a0[3] + a1[3] + a2[3] + a3[3], 0.f);
  *(float4*)(out + (size_t)node * D_OUT + lane * 4) = o;
}

extern "C" void kernel_launch(void* const* d_in, const int* in_sizes, int n_in,
                              void* d_out, int out_size, void* d_ws, size_t ws_size,
                              hipStream_t stream) {
  const float* x    = (const float*)d_in[0];
  const float* W    = (const float*)d_in[1];
  const float* ev   = (const float*)d_in[2];
  const int*   esrc = (const int*)d_in[3];
  const int*   edst = (const int*)d_in[4];
  float* out = (float*)d_out;

  char* ws = (char*)d_ws;
  size_t off = 0;
  auto alloc = [&](size_t bytes) -> void* {
    off = (off + 255) & ~(size_t)255;
    void* p = ws + off;
    off += bytes;
    return p;
  };
  u16*   xb        = (u16*)  alloc((size_t)M_PAD * D_IN * 2);
  u16*   wt        = (u16*)  alloc((size_t)D_OUT * D_IN * 2);
  u16*   hb        = (u16*)  alloc((size_t)N_NODES * D_OUT * 2);
  int*   counts    = (int*)  alloc((size_t)N_NODES * 4);
  int*   row_start = (int*)  alloc((size_t)(N_NODES + 1) * 4);
  int*   rank      = (int*)  alloc((size_t)N_EDGES * 4);
  int*   btot      = (int*)  alloc(256 * 4);
  int2*  pack      = (int2*) alloc((size_t)N_EDGES * 8);

  long n_valid = (long)N_NODES * D_IN;        // 25,600,000 (mult of 8)
  long n_total = (long)M_PAD * D_IN;          // 25,624,576 (mult of 8)
  int nb = (N_NODES + 255) / 256;             // 196 scan blocks

  k_zero<<<nb, 256, 0, stream>>>(counts, N_NODES);
  k_convert_x<<<(int)(n_total / 8 / 256), 256, 0, stream>>>(x, xb, n_valid, n_total);
  k_convert_w<<<(D_IN * D_OUT) / 256, 256, 0, stream>>>(W, wt);
  k_hist<<<N_EDGES / 256, 256, 0, stream>>>(edst, counts, rank, N_EDGES);
  k_scan1<<<nb, 256, 0, stream>>>(counts, row_start, btot, N_NODES);
  k_scan2<<<1, 256, 0, stream>>>(btot, nb);
  k_scan3<<<nb, 256, 0, stream>>>(counts, row_start, btot, N_NODES);
  k_scatter<<<N_EDGES / 256, 256, 0, stream>>>(esrc, edst, ev, row_start, rank, pack, N_EDGES);
  k_gemm<<<(M_PAD / 128) * (D_OUT / 128), 256, 0, stream>>>(xb, wt, hb, N_NODES);
  k_agg<<<(N_NODES + 3) / 4, 256, 0, stream>>>(hb, row_start, pack, out, N_NODES);
}